// Round 5
// baseline (224.274 us; speedup 1.0000x reference)
//
#include <hip/hip_runtime.h>
#include <hip/hip_bf16.h>

// Problem constants
#define NROWS 65536      // 64*32*32
#define DIM   256
#define NCODE 1024
#define OUT_ELEMS 16777216  // NROWS*DIM

typedef __attribute__((ext_vector_type(8))) short bf16x8;
typedef __attribute__((ext_vector_type(4))) float f32x4;

__device__ __forceinline__ unsigned umin_(unsigned a, unsigned b) { return a < b ? a : b; }

// RNE float->bf16 (finite inputs) — must stay bit-identical across rounds
__device__ __forceinline__ unsigned short f2bf(float f) {
    unsigned b = __builtin_bit_cast(unsigned, f);
    return (unsigned short)((b + 0x7FFFu + ((b >> 16) & 1u)) >> 16);
}

// ---------------------------------------------------------------------------
// K_prep: blocks 0..127: codebook fp32 -> bf16 in MFMA B-fragment order.
//   eb[((t*8+ks)*64 + lane)*8 + j] = e[n][k], n=t*16+(lane&15), k=ks*32+(lane>>4)*8+j
// blocks 128..131: per-code squared norms + 0.25 key offset (fp32 exact).
// ---------------------------------------------------------------------------
__global__ __launch_bounds__(256)
void k_prep(const float* __restrict__ e, float* __restrict__ seb,
            unsigned short* __restrict__ eb) {
    int b = blockIdx.x;
    if (b < 128) {
        int g = b * 256 + threadIdx.x;   // 0 .. 32767
        int lane = g & 63;
        int ks   = (g >> 6) & 7;
        int t    = g >> 9;
        int n  = t * 16 + (lane & 15);
        int k0 = ks * 32 + (lane >> 4) * 8;
        const float* src = e + (size_t)n * DIM + k0;
        bf16x8 o;
        #pragma unroll
        for (int j = 0; j < 8; ++j) o[j] = (short)f2bf(src[j]);
        *(bf16x8*)(eb + (size_t)g * 8) = o;
    } else {
        int c = (b - 128) * 256 + threadIdx.x;
        const float4* r = (const float4*)(e + (size_t)c * DIM);
        float s = 0.f;
        #pragma unroll
        for (int i = 0; i < DIM / 4; ++i) {
            float4 v = r[i];
            s += v.x * v.x + v.y * v.y + v.z * v.z + v.w * v.w;
        }
        seb[c] = s + 0.25f;
    }
}

// ---------------------------------------------------------------------------
// K1: MFMA distance-argmin.  Grid 1024 blocks x 256 thr (4 waves).
// Block rows = 64.  Wave w: row-group grp=w>>1 (32 rows), code-half half=w&1
// (512 codes = 32 tiles of 16).  A = af[2 stripes][8 ks] (64 VGPR), converted
// fp32->bf16 in-register.  B fragments ping-pong double-buffered (2x32 VGPR)
// so the next tile's 8 loads fly under the current tile's 16 MFMAs.
// ~175 live VGPR -> no spill at launch_bounds(256,2).
// 16x16x32 MFMA layouts (verified m89/m91): A[m=lane&15][k=(lane>>4)*8+j],
// B[n=lane&15][k=same], D col(code)=lane&15, row(x-row)=(lane>>4)*4+reg.
// argmin via packed key: (bits(se+0.25-2dot) & ~1023) | code -> min_u32.
// Histogram fused into the epilogue.
// ---------------------------------------------------------------------------
#define COMPUTE_TILE(FR, SE, TI)                                              \
    {                                                                         \
        f32x4 acc[2];                                                         \
        acc[0] = (f32x4){0.f, 0.f, 0.f, 0.f};                                 \
        acc[1] = (f32x4){0.f, 0.f, 0.f, 0.f};                                 \
        _Pragma("unroll")                                                     \
        for (int ks = 0; ks < 8; ++ks) {                                      \
            acc[0] = __builtin_amdgcn_mfma_f32_16x16x32_bf16(af[0][ks], FR[ks], acc[0], 0, 0, 0); \
            acc[1] = __builtin_amdgcn_mfma_f32_16x16x32_bf16(af[1][ks], FR[ks], acc[1], 0, 0, 0); \
        }                                                                     \
        unsigned nl = (unsigned)((TI) * 16) | (unsigned)lr;                   \
        _Pragma("unroll")                                                     \
        for (int s = 0; s < 2; ++s)                                           \
            _Pragma("unroll")                                                 \
            for (int r = 0; r < 4; ++r) {                                     \
                float sc = fmaf(-2.0f, acc[s][r], (SE));                      \
                unsigned u = (__builtin_bit_cast(unsigned, sc) & 0xFFFFFC00u) | nl; \
                best[s][r] = umin_(best[s][r], u);                            \
            }                                                                 \
    }

__global__ __launch_bounds__(256, 2)
void k_argmin(const float* __restrict__ x,
              const unsigned short* __restrict__ eb,
              const float* __restrict__ seb,
              int* __restrict__ idx_out, int* __restrict__ counts) {
    const int t = threadIdx.x;
    const int w = t >> 6;            // wave 0..3
    const int l = t & 63;
    const int lr = l & 15;           // frag row/col index
    const int lh = l >> 4;           // quad
    const int grp  = w >> 1;         // row group (32 rows)
    const int half = w & 1;          // code half (512 codes)
    const int row0 = blockIdx.x * 64;

    // A fragments: 2 stripes x 8 ksteps (64 VGPR), fp32 loads + in-reg cvt
    bf16x8 af[2][8];
    #pragma unroll
    for (int s = 0; s < 2; ++s) {
        const float* rp = x + (size_t)(row0 + grp * 32 + s * 16 + lr) * DIM + lh * 8;
        #pragma unroll
        for (int ks = 0; ks < 8; ++ks) {
            float4 a = *(const float4*)(rp + ks * 32);
            float4 b = *(const float4*)(rp + ks * 32 + 4);
            bf16x8 o;
            o[0] = (short)f2bf(a.x); o[1] = (short)f2bf(a.y);
            o[2] = (short)f2bf(a.z); o[3] = (short)f2bf(a.w);
            o[4] = (short)f2bf(b.x); o[5] = (short)f2bf(b.y);
            o[6] = (short)f2bf(b.z); o[7] = (short)f2bf(b.w);
            af[s][ks] = o;
        }
    }

    unsigned best[2][4];
    #pragma unroll
    for (int s = 0; s < 2; ++s)
        #pragma unroll
        for (int r = 0; r < 4; ++r) best[s][r] = 0xFFFFFFFFu;

    const int tile0 = half * 32;
    const unsigned short* bbase = eb + (size_t)tile0 * 4096 + (size_t)l * 8;
    const float* sbase = seb + tile0 * 16 + lr;

    // ping-pong B buffers
    bf16x8 pa[8], pb[8];
    #pragma unroll
    for (int ks = 0; ks < 8; ++ks) pa[ks] = *(const bf16x8*)(bbase + ks * 512);
    float seA = sbase[0];

    #pragma unroll 1
    for (int tp = 0; tp < 16; ++tp) {
        const int tB = 2 * tp + 1;
        const unsigned short* bpB = bbase + (size_t)tB * 4096;
        #pragma unroll
        for (int ks = 0; ks < 8; ++ks) pb[ks] = *(const bf16x8*)(bpB + ks * 512);
        float seB = sbase[tB * 16];

        COMPUTE_TILE(pa, seA, tile0 + 2 * tp)

        const int tN = (tp < 15) ? (2 * tp + 2) : 0;   // last iter: harmless reload
        const unsigned short* bpN = bbase + (size_t)tN * 4096;
        #pragma unroll
        for (int ks = 0; ks < 8; ++ks) pa[ks] = *(const bf16x8*)(bpN + ks * 512);
        float seN = sbase[tN * 16];

        COMPUTE_TILE(pb, seB, tile0 + tB)
        seA = seN;
    }

    // reduce over the 16 code-lanes (same lh): xor 1,2,4,8
    #pragma unroll
    for (int s = 0; s < 2; ++s)
        #pragma unroll
        for (int r = 0; r < 4; ++r) {
            unsigned b = best[s][r];
            #pragma unroll
            for (int m = 1; m <= 8; m <<= 1)
                b = umin_(b, (unsigned)__shfl_xor((int)b, m, 64));
            best[s][r] = b;
        }

    __shared__ unsigned keys[4][32];
    if (lr == 0) {
        #pragma unroll
        for (int s = 0; s < 2; ++s)
            #pragma unroll
            for (int r = 0; r < 4; ++r)
                keys[w][s * 16 + lh * 4 + r] = best[s][r];
    }
    __syncthreads();
    if (t < 64) {
        int g2 = t >> 5;             // row group
        int wi = t & 31;
        unsigned k2 = umin_(keys[g2 * 2][wi], keys[g2 * 2 + 1][wi]);
        int code = (int)(k2 & 1023u);
        idx_out[row0 + t] = code;
        atomicAdd(&counts[code], 1);
    }
}

// ---------------------------------------------------------------------------
// K2: gather + straight-through output + loss sum (fp32 exact).
// Wave owns 8 rows; idx loads, x loads, gathers all issued before use.
// ---------------------------------------------------------------------------
__global__ __launch_bounds__(256)
void k_out_loss(const float* __restrict__ x, const float* __restrict__ e,
                const int* __restrict__ idx, float* __restrict__ out,
                double* __restrict__ sumsq) {
    const int w = threadIdx.x >> 6;
    const int l = threadIdx.x & 63;
    const int row0 = blockIdx.x * 32 + w * 8;

    int k[8];
    #pragma unroll
    for (int r = 0; r < 8; ++r) k[r] = idx[row0 + r];
    float4 xv[8];
    #pragma unroll
    for (int r = 0; r < 8; ++r) xv[r] = ((const float4*)x)[(size_t)(row0 + r) * 64 + l];
    float4 qv[8];
    #pragma unroll
    for (int r = 0; r < 8; ++r) qv[r] = ((const float4*)e)[(size_t)k[r] * 64 + l];

    float local = 0.f;
    #pragma unroll
    for (int r = 0; r < 8; ++r) {
        float4 d, o;
        d.x = qv[r].x - xv[r].x; d.y = qv[r].y - xv[r].y;
        d.z = qv[r].z - xv[r].z; d.w = qv[r].w - xv[r].w;
        o.x = xv[r].x + d.x;  o.y = xv[r].y + d.y;
        o.z = xv[r].z + d.z;  o.w = xv[r].w + d.w;
        ((float4*)out)[(size_t)(row0 + r) * 64 + l] = o;
        local += d.x * d.x + d.y * d.y + d.z * d.z + d.w * d.w;
    }
    #pragma unroll
    for (int m = 32; m >= 1; m >>= 1) local += __shfl_xor(local, m, 64);
    __shared__ float red[4];
    if (l == 0) red[w] = local;
    __syncthreads();
    if (threadIdx.x == 0) {
        float s = red[0] + red[1] + red[2] + red[3];
        atomicAdd(sumsq, (double)s);
    }
}

// ---------------------------------------------------------------------------
// K4: finalize loss + perplexity (single block)
// ---------------------------------------------------------------------------
__global__ __launch_bounds__(256)
void k_fin(const int* __restrict__ counts, const double* __restrict__ sumsq,
           float* __restrict__ out_scalars) {
    float local = 0.f;
    for (int c = threadIdx.x; c < NCODE; c += 256) {
        float p = (float)counts[c] * (1.0f / 65536.0f);
        local += p * logf(p + 1e-10f);
    }
    #pragma unroll
    for (int m = 32; m >= 1; m >>= 1) local += __shfl_xor(local, m, 64);
    __shared__ float red[4];
    if ((threadIdx.x & 63) == 0) red[threadIdx.x >> 6] = local;
    __syncthreads();
    if (threadIdx.x == 0) {
        float s = red[0] + red[1] + red[2] + red[3];
        float perp = expf(-s);
        float m = (float)(*sumsq * (1.0 / 16777216.0));
        float loss = m + 0.25f * m;
        out_scalars[0] = loss;
        out_scalars[1] = perp;
    }
}

// ---------------------------------------------------------------------------
extern "C" void kernel_launch(void* const* d_in, const int* in_sizes, int n_in,
                              void* d_out, int out_size, void* d_ws, size_t ws_size,
                              hipStream_t stream) {
    const float* x   = (const float*)d_in[0];   // [65536, 256]
    const float* emb = (const float*)d_in[1];   // [1024, 256]
    float* out = (float*)d_out;                 // [16777216 + 2]

    // small workspace
    int*    idx    = (int*)d_ws;                            // 256 KB
    float*  seb    = (float*)((char*)d_ws + 262144);        // 4 KB
    int*    counts = (int*)((char*)d_ws + 266240);          // 4 KB
    double* sumsq  = (double*)((char*)d_ws + 270336);       // 8 B

    // eb scratch lives in d_out: consumed by k_argmin BEFORE k_out_loss
    // overwrites d_out (stream-ordered).
    unsigned short* eb = (unsigned short*)((char*)d_out + 33554432); // 512 KB

    hipMemsetAsync((char*)d_ws + 266240, 0, 4096 + 8, stream);

    k_prep    <<<132,         256, 0, stream>>>(emb, seb, eb);
    k_argmin  <<<NROWS / 64,  256, 0, stream>>>(x, eb, seb, idx, counts);
    k_out_loss<<<NROWS / 32,  256, 0, stream>>>(x, emb, idx, out, sumsq);
    k_fin     <<<1,           256, 0, stream>>>(counts, sumsq, out + OUT_ELEMS);
}

// Round 6
// 209.308 us; speedup vs baseline: 1.0715x; 1.0715x over previous
//
#include <hip/hip_runtime.h>
#include <hip/hip_bf16.h>

// Problem constants
#define NROWS 65536      // 64*32*32
#define DIM   256
#define NCODE 1024
#define OUT_ELEMS 16777216  // NROWS*DIM

typedef __attribute__((ext_vector_type(8))) short bf16x8;
typedef __attribute__((ext_vector_type(4))) float f32x4;

__device__ __forceinline__ unsigned umin_(unsigned a, unsigned b) { return a < b ? a : b; }

// RNE float->bf16 (finite inputs) — must stay bit-identical across rounds
__device__ __forceinline__ unsigned short f2bf(float f) {
    unsigned b = __builtin_bit_cast(unsigned, f);
    return (unsigned short)((b + 0x7FFFu + ((b >> 16) & 1u)) >> 16);
}

// async global->LDS, 16B per lane: lane l deposits at lds_base + l*16
__device__ __forceinline__ void gload_lds16(const void* g, void* l) {
    __builtin_amdgcn_global_load_lds(
        (const __attribute__((address_space(1))) unsigned int*)g,
        (__attribute__((address_space(3))) unsigned int*)l, 16, 0, 0);
}

// ---------------------------------------------------------------------------
// K_prep: blocks 0..127: codebook fp32 -> bf16 in MFMA B-fragment order.
//   eb[((t*8+ks)*64 + lane)*8 + j] = e[n][k], n=t*16+(lane&15), k=ks*32+(lane>>4)*8+j
//   (tile t = 4096 shorts = 8 KB contiguous — exactly the LDS staging order)
// blocks 128..131: per-code squared norms + 0.25 key offset (fp32 exact).
// ---------------------------------------------------------------------------
__global__ __launch_bounds__(256)
void k_prep(const float* __restrict__ e, float* __restrict__ seb,
            unsigned short* __restrict__ eb) {
    int b = blockIdx.x;
    if (b < 128) {
        int g = b * 256 + threadIdx.x;   // 0 .. 32767
        int lane = g & 63;
        int ks   = (g >> 6) & 7;
        int t    = g >> 9;
        int n  = t * 16 + (lane & 15);
        int k0 = ks * 32 + (lane >> 4) * 8;
        const float* src = e + (size_t)n * DIM + k0;
        bf16x8 o;
        #pragma unroll
        for (int j = 0; j < 8; ++j) o[j] = (short)f2bf(src[j]);
        *(bf16x8*)(eb + (size_t)g * 8) = o;
    } else {
        int c = (b - 128) * 256 + threadIdx.x;
        const float4* r = (const float4*)(e + (size_t)c * DIM);
        float s = 0.f;
        #pragma unroll
        for (int i = 0; i < DIM / 4; ++i) {
            float4 v = r[i];
            s += v.x * v.x + v.y * v.y + v.z * v.z + v.w * v.w;
        }
        seb[c] = s + 0.25f;
    }
}

// ---------------------------------------------------------------------------
// K1: MFMA distance-argmin, LDS-shared B.
// Grid 512 blocks x 128 thr (2 waves).  Block rows = 128; wave w owns rows
// [row0 + w*64, +64) as 4 stripes x 16.  Both waves scan ALL 1024 codes.
// B staged to LDS in 64-code chunks (32 KB), double-buffered (64 KB LDS),
// via global_load_lds(16B) — each wave stages half a chunk (16 instrs).
// L2 B-traffic: 512 blocks x 512 KB = 256 MB (was 1 GB streaming per-wave).
// se loads are issued BEFORE the stage so their vmcnt wait doesn't drain
// the prefetch queue.
// MFMA layouts (proven R3-R5): A[m=lane&15][k=(lane>>4)*8+j],
// B[n=lane&15][k=same], D col(code)=lane&15, row=(lane>>4)*4+reg.
// argmin key: (bits(se+0.25-2dot) & ~1023) | code -> min_u32. Hist fused.
// ---------------------------------------------------------------------------
__global__ __launch_bounds__(128, 2)
void k_argmin(const float* __restrict__ x,
              const unsigned short* __restrict__ eb,
              const float* __restrict__ seb,
              int* __restrict__ idx_out, int* __restrict__ counts) {
    __shared__ unsigned short bs[2][16384];   // 2 x 32 KB

    const int t = threadIdx.x;
    const int w = t >> 6;            // wave 0/1
    const int l = t & 63;
    const int lr = l & 15;
    const int lh = l >> 4;
    const int row0 = blockIdx.x * 128;

    // A fragments: 4 stripes x 8 ksteps (128 VGPR), fp32 loads + in-reg cvt
    bf16x8 af[4][8];
    #pragma unroll
    for (int s = 0; s < 4; ++s) {
        const float* rp = x + (size_t)(row0 + w * 64 + s * 16 + lr) * DIM + lh * 8;
        #pragma unroll
        for (int ks = 0; ks < 8; ++ks) {
            float4 a = *(const float4*)(rp + ks * 32);
            float4 b = *(const float4*)(rp + ks * 32 + 4);
            bf16x8 o;
            o[0] = (short)f2bf(a.x); o[1] = (short)f2bf(a.y);
            o[2] = (short)f2bf(a.z); o[3] = (short)f2bf(a.w);
            o[4] = (short)f2bf(b.x); o[5] = (short)f2bf(b.y);
            o[6] = (short)f2bf(b.z); o[7] = (short)f2bf(b.w);
            af[s][ks] = o;
        }
    }

    unsigned best[4][4];
    #pragma unroll
    for (int s = 0; s < 4; ++s)
        #pragma unroll
        for (int r = 0; r < 4; ++r) best[s][r] = 0xFFFFFFFFu;

    // prologue: stage chunk 0 into buf 0 (this wave's half)
    {
        const unsigned short* src = eb + (size_t)w * 8192 + (size_t)l * 8;
        unsigned short* dst = &bs[0][w * 8192];
        #pragma unroll
        for (int i = 0; i < 16; ++i)
            gload_lds16(src + i * 512, dst + i * 512);
    }

    #pragma unroll 1
    for (int cq = 0; cq < 16; ++cq) {
        // se for this chunk's 4 tiles — issue FIRST (stays ahead of prefetch in vmcnt order)
        float sev[4];
        #pragma unroll
        for (int j = 0; j < 4; ++j) sev[j] = seb[(cq * 4 + j) * 16 + lr];

        __syncthreads();   // chunk cq staged; prev chunk's readers done

        if (cq < 15) {     // prefetch chunk cq+1 into the other buffer
            const unsigned short* src = eb + (size_t)(cq + 1) * 16384 + (size_t)w * 8192 + (size_t)l * 8;
            unsigned short* dst = &bs[(cq + 1) & 1][w * 8192];
            #pragma unroll
            for (int i = 0; i < 16; ++i)
                gload_lds16(src + i * 512, dst + i * 512);
        }

        const unsigned short* lb = &bs[cq & 1][0];
        #pragma unroll
        for (int j = 0; j < 4; ++j) {
            const int ti = cq * 4 + j;
            const unsigned short* bp = lb + j * 4096 + l * 8;
            bf16x8 bfr[8];
            #pragma unroll
            for (int ks = 0; ks < 8; ++ks)
                bfr[ks] = *(const bf16x8*)(bp + ks * 512);

            f32x4 acc[4];
            #pragma unroll
            for (int s = 0; s < 4; ++s) acc[s] = (f32x4){0.f, 0.f, 0.f, 0.f};
            #pragma unroll
            for (int ks = 0; ks < 8; ++ks)
                #pragma unroll
                for (int s = 0; s < 4; ++s)
                    acc[s] = __builtin_amdgcn_mfma_f32_16x16x32_bf16(af[s][ks], bfr[ks], acc[s], 0, 0, 0);

            unsigned nl = (unsigned)(ti * 16) | (unsigned)lr;
            #pragma unroll
            for (int s = 0; s < 4; ++s)
                #pragma unroll
                for (int r = 0; r < 4; ++r) {
                    float sc = fmaf(-2.0f, acc[s][r], sev[j]);   // >0 by construction
                    unsigned u = (__builtin_bit_cast(unsigned, sc) & 0xFFFFFC00u) | nl;
                    best[s][r] = umin_(best[s][r], u);
                }
        }
    }

    // reduce over the 16 code-lanes (same lh): xor 1,2,4,8
    #pragma unroll
    for (int s = 0; s < 4; ++s)
        #pragma unroll
        for (int r = 0; r < 4; ++r) {
            unsigned b = best[s][r];
            #pragma unroll
            for (int m = 1; m <= 8; m <<= 1)
                b = umin_(b, (unsigned)__shfl_xor((int)b, m, 64));
            best[s][r] = b;
        }

    if (lr == 0) {
        #pragma unroll
        for (int s = 0; s < 4; ++s)
            #pragma unroll
            for (int r = 0; r < 4; ++r) {
                int code = (int)(best[s][r] & 1023u);
                idx_out[row0 + w * 64 + s * 16 + lh * 4 + r] = code;
                atomicAdd(&counts[code], 1);
            }
    }
}

// ---------------------------------------------------------------------------
// K2: gather + straight-through output + loss sum (fp32 exact).
// Wave owns 8 rows; idx loads, x loads, gathers all issued before use.
// ---------------------------------------------------------------------------
__global__ __launch_bounds__(256)
void k_out_loss(const float* __restrict__ x, const float* __restrict__ e,
                const int* __restrict__ idx, float* __restrict__ out,
                double* __restrict__ sumsq) {
    const int w = threadIdx.x >> 6;
    const int l = threadIdx.x & 63;
    const int row0 = blockIdx.x * 32 + w * 8;

    int k[8];
    #pragma unroll
    for (int r = 0; r < 8; ++r) k[r] = idx[row0 + r];
    float4 xv[8];
    #pragma unroll
    for (int r = 0; r < 8; ++r) xv[r] = ((const float4*)x)[(size_t)(row0 + r) * 64 + l];
    float4 qv[8];
    #pragma unroll
    for (int r = 0; r < 8; ++r) qv[r] = ((const float4*)e)[(size_t)k[r] * 64 + l];

    float local = 0.f;
    #pragma unroll
    for (int r = 0; r < 8; ++r) {
        float4 d, o;
        d.x = qv[r].x - xv[r].x; d.y = qv[r].y - xv[r].y;
        d.z = qv[r].z - xv[r].z; d.w = qv[r].w - xv[r].w;
        o.x = xv[r].x + d.x;  o.y = xv[r].y + d.y;
        o.z = xv[r].z + d.z;  o.w = xv[r].w + d.w;
        ((float4*)out)[(size_t)(row0 + r) * 64 + l] = o;
        local += d.x * d.x + d.y * d.y + d.z * d.z + d.w * d.w;
    }
    #pragma unroll
    for (int m = 32; m >= 1; m >>= 1) local += __shfl_xor(local, m, 64);
    __shared__ float red[4];
    if (l == 0) red[w] = local;
    __syncthreads();
    if (threadIdx.x == 0) {
        float s = red[0] + red[1] + red[2] + red[3];
        atomicAdd(sumsq, (double)s);
    }
}

// ---------------------------------------------------------------------------
// K4: finalize loss + perplexity (single block)
// ---------------------------------------------------------------------------
__global__ __launch_bounds__(256)
void k_fin(const int* __restrict__ counts, const double* __restrict__ sumsq,
           float* __restrict__ out_scalars) {
    float local = 0.f;
    for (int c = threadIdx.x; c < NCODE; c += 256) {
        float p = (float)counts[c] * (1.0f / 65536.0f);
        local += p * logf(p + 1e-10f);
    }
    #pragma unroll
    for (int m = 32; m >= 1; m >>= 1) local += __shfl_xor(local, m, 64);
    __shared__ float red[4];
    if ((threadIdx.x & 63) == 0) red[threadIdx.x >> 6] = local;
    __syncthreads();
    if (threadIdx.x == 0) {
        float s = red[0] + red[1] + red[2] + red[3];
        float perp = expf(-s);
        float m = (float)(*sumsq * (1.0 / 16777216.0));
        float loss = m + 0.25f * m;
        out_scalars[0] = loss;
        out_scalars[1] = perp;
    }
}

// ---------------------------------------------------------------------------
extern "C" void kernel_launch(void* const* d_in, const int* in_sizes, int n_in,
                              void* d_out, int out_size, void* d_ws, size_t ws_size,
                              hipStream_t stream) {
    const float* x   = (const float*)d_in[0];   // [65536, 256]
    const float* emb = (const float*)d_in[1];   // [1024, 256]
    float* out = (float*)d_out;                 // [16777216 + 2]

    // small workspace
    int*    idx    = (int*)d_ws;                            // 256 KB
    float*  seb    = (float*)((char*)d_ws + 262144);        // 4 KB
    int*    counts = (int*)((char*)d_ws + 266240);          // 4 KB
    double* sumsq  = (double*)((char*)d_ws + 270336);       // 8 B

    // eb scratch lives in d_out: consumed by k_argmin BEFORE k_out_loss
    // overwrites d_out (stream-ordered).
    unsigned short* eb = (unsigned short*)((char*)d_out + 33554432); // 512 KB

    hipMemsetAsync((char*)d_ws + 266240, 0, 4096 + 8, stream);

    k_prep    <<<132,         256, 0, stream>>>(emb, seb, eb);
    k_argmin  <<<NROWS / 128, 128, 0, stream>>>(x, eb, seb, idx, counts);
    k_out_loss<<<NROWS / 32,  256, 0, stream>>>(x, emb, idx, out, sumsq);
    k_fin     <<<1,           256, 0, stream>>>(counts, sumsq, out + OUT_ELEMS);
}